// Round 4
// baseline (744.437 us; speedup 1.0000x reference)
//
#include <hip/hip_runtime.h>
#include <hip/hip_fp16.h>

#define K_NB 81
#define OUTC 8
#define BLK 256
#define KT 16   // k-tile staged in LDS; 80 = 5*16 (k=0 handled in prologue)

typedef float v2f __attribute__((ext_vector_type(2)));   // clang vector: ok for nontemporal builtins

// W2[k][c][l] = dw[k][c] * weight[c][k][l], flat as w2[k*32 + c*8 + l]
__global__ void prep_w2(const float* __restrict__ dw,
                        const float* __restrict__ wt,
                        float* __restrict__ w2) {
    int i = blockIdx.x * blockDim.x + threadIdx.x;
    if (i < K_NB * 32) {
        int k = i >> 5;
        int c = (i >> 3) & 3;
        int l = i & 7;
        w2[i] = dw[k * 4 + c] * wt[(c * K_NB + k) * OUTC + l];
    }
}

union F2H { float f; __half2 h; };

// points [N,3] fp32 -> ph[N] = {half x, half y, half z, half 0} (8B, aligned)
__global__ void repack_points(const float* __restrict__ pts,
                              v2f* __restrict__ ph, int N) {
    int n = blockIdx.x * blockDim.x + threadIdx.x;
    if (n >= N) return;
    float x = pts[3 * n + 0], y = pts[3 * n + 1], z = pts[3 * n + 2];
    F2H a, b;
    a.h = __floats2half2_rn(x, y);
    b.h = __floats2half2_rn(z, 0.f);
    v2f v; v.x = a.f; v.y = b.f;
    ph[n] = v;
}

__global__ __launch_bounds__(BLK) void conv_main_h(
    const float* __restrict__ points,   // fp32, coalesced self-load
    const v2f*   __restrict__ ph,       // half4-packed points
    const int*   __restrict__ indices,
    const float* __restrict__ w2,
    const float* __restrict__ bias,
    float*       __restrict__ out,
    int N) {
    __shared__ int sidx[BLK * (KT + 1)];  // pitch 17: 2-way bank alias = free

    const int tid = threadIdx.x;
    const int n0  = blockIdx.x * BLK;
    const int n   = n0 + tid;
    const bool valid = n < N;
    const int nc = valid ? n : (N - 1);   // clamped, for safe loads

    const float px = points[nc * 3 + 0];
    const float py = points[nc * 3 + 1];
    const float pz = points[nc * 3 + 2];

    float acc[OUTC];
#pragma unroll
    for (int l = 0; l < OUTC; ++l) {
        float a = bias[l] + w2[24 + l];           // k=0: dist feature = 1.0
        a = fmaf(px, w2[0 + l], a);
        a = fmaf(py, w2[8 + l], a);
        a = fmaf(pz, w2[16 + l], a);
        acc[l] = a;
    }

    for (int t = 0; t < 5; ++t) {
        __syncthreads();
        // stage indices[n0..n0+255][1+t*16 .. +15] coalesced; clamp rows past N
        // so every LDS slot holds a VALID index (gathers run unpredicated).
#pragma unroll
        for (int i = 0; i < KT; ++i) {
            int e   = i * BLK + tid;
            int row = e >> 4;
            int col = e & 15;
            int gr  = n0 + row;
            if (gr >= N) gr = N - 1;
            sidx[row * (KT + 1) + col] =
                __builtin_nontemporal_load(&indices[gr * K_NB + 1 + t * KT + col]);
        }
        __syncthreads();

        // phase 1: pull all ids for this thread from LDS
        int ids[KT];
#pragma unroll
        for (int j = 0; j < KT; ++j)
            ids[j] = sidx[tid * (KT + 1) + j];

        // phase 2: issue ALL gathers back-to-back (max outstanding vmem),
        // nontemporal -> skip pointless L1 allocation for random lines
        v2f r[KT];
#pragma unroll
        for (int j = 0; j < KT; ++j)
            r[j] = __builtin_nontemporal_load(&ph[ids[j]]);

        // phase 3: consume (oldest first, so vmcnt waits overlap issue)
#pragma unroll
        for (int j = 0; j < KT; ++j) {
            const int k = 1 + t * KT + j;
            F2H u0, u1; u0.f = r[j].x; u1.f = r[j].y;
            const float2 fxy = __half22float2(u0.h);
            const float  qx = fxy.x, qy = fxy.y;
            const float  qz = __half2float(__low2half(u1.h));
            const float dx = qx - px, dy = qy - py, dz = qz - pz;
            const float dist = fmaf(dx, dx, fmaf(dy, dy, fmaf(dz, dz, 1.0f)));
            const float* __restrict__ w = w2 + k * 32;  // uniform -> s_load
#pragma unroll
            for (int l = 0; l < OUTC; ++l) {
                acc[l] = fmaf(qx, w[l],
                         fmaf(qy, w[8 + l],
                         fmaf(qz, w[16 + l],
                         fmaf(dist, w[24 + l], acc[l]))));
            }
        }
    }

    if (valid) {
        float4* o = (float4*)(out + (long)n * OUTC);
        o[0] = make_float4(acc[0], acc[1], acc[2], acc[3]);
        o[1] = make_float4(acc[4], acc[5], acc[6], acc[7]);
    }
}

// ---------- fp32 fallback if ws too small ----------
__global__ __launch_bounds__(BLK) void conv_main_f32(
    const float* __restrict__ points,
    const int*   __restrict__ indices,
    const float* __restrict__ w2,
    const float* __restrict__ bias,
    float*       __restrict__ out,
    int N) {
    __shared__ int sidx[BLK * (KT + 1)];
    const int tid = threadIdx.x;
    const int n0  = blockIdx.x * BLK;
    const int n   = n0 + tid;
    const bool valid = n < N;
    const int nc = valid ? n : (N - 1);

    const float px = points[nc * 3 + 0];
    const float py = points[nc * 3 + 1];
    const float pz = points[nc * 3 + 2];
    float acc[OUTC];
#pragma unroll
    for (int l = 0; l < OUTC; ++l) {
        float a = bias[l] + w2[24 + l];
        a = fmaf(px, w2[0 + l], a);
        a = fmaf(py, w2[8 + l], a);
        a = fmaf(pz, w2[16 + l], a);
        acc[l] = a;
    }
    for (int t = 0; t < 5; ++t) {
        __syncthreads();
#pragma unroll
        for (int i = 0; i < KT; ++i) {
            int e = i * BLK + tid;
            int row = e >> 4, col = e & 15;
            int gr = n0 + row;
            if (gr >= N) gr = N - 1;
            sidx[row * (KT + 1) + col] = indices[gr * K_NB + 1 + t * KT + col];
        }
        __syncthreads();
#pragma unroll
        for (int j = 0; j < KT; ++j) {
            const int k  = 1 + t * KT + j;
            const int id = sidx[tid * (KT + 1) + j];
            const float qx = points[id * 3 + 0];
            const float qy = points[id * 3 + 1];
            const float qz = points[id * 3 + 2];
            const float dx = qx - px, dy = qy - py, dz = qz - pz;
            const float dist = fmaf(dx, dx, fmaf(dy, dy, fmaf(dz, dz, 1.0f)));
            const float* __restrict__ w = w2 + k * 32;
#pragma unroll
            for (int l = 0; l < OUTC; ++l) {
                acc[l] = fmaf(qx, w[l],
                         fmaf(qy, w[8 + l],
                         fmaf(qz, w[16 + l],
                         fmaf(dist, w[24 + l], acc[l]))));
            }
        }
    }
    if (valid) {
        float4* o = (float4*)(out + (long)n * OUTC);
        o[0] = make_float4(acc[0], acc[1], acc[2], acc[3]);
        o[1] = make_float4(acc[4], acc[5], acc[6], acc[7]);
    }
}

extern "C" void kernel_launch(void* const* d_in, const int* in_sizes, int n_in,
                              void* d_out, int out_size, void* d_ws, size_t ws_size,
                              hipStream_t stream) {
    const float* points  = (const float*)d_in[0];
    const int*   indices = (const int*)  d_in[1];
    const float* dw      = (const float*)d_in[2];
    const float* wt      = (const float*)d_in[3];
    const float* bias    = (const float*)d_in[4];
    float*       out     = (float*)d_out;

    const int N = in_sizes[0] / 3;

    const size_t ph_bytes = (size_t)N * 8;
    const size_t need     = ph_bytes + K_NB * 32 * sizeof(float);

    if (ws_size >= need) {
        v2f*   ph = (v2f*)d_ws;
        float* w2 = (float*)((char*)d_ws + ph_bytes);
        hipLaunchKernelGGL(prep_w2, dim3((K_NB * 32 + BLK - 1) / BLK), dim3(BLK),
                           0, stream, dw, wt, w2);
        hipLaunchKernelGGL(repack_points, dim3((N + BLK - 1) / BLK), dim3(BLK),
                           0, stream, points, ph, N);
        hipLaunchKernelGGL(conv_main_h, dim3((N + BLK - 1) / BLK), dim3(BLK),
                           0, stream, points, ph, indices, w2, bias, out, N);
    } else {
        float* w2 = (float*)d_ws;
        hipLaunchKernelGGL(prep_w2, dim3((K_NB * 32 + BLK - 1) / BLK), dim3(BLK),
                           0, stream, dw, wt, w2);
        hipLaunchKernelGGL(conv_main_f32, dim3((N + BLK - 1) / BLK), dim3(BLK),
                           0, stream, points, indices, w2, bias, out, N);
    }
}

// Round 5
// 441.769 us; speedup vs baseline: 1.6851x; 1.6851x over previous
//
#include <hip/hip_runtime.h>
#include <hip/hip_fp16.h>

#define K_NB 81
#define OUTC 8
#define BLK 256
#define KT 16   // k-tile staged in LDS; 80 = 5*16 (k=0 handled in prologue)

typedef float v2f __attribute__((ext_vector_type(2)));

// W2[k][c][l] = dw[k][c] * weight[c][k][l], flat as w2[k*32 + c*8 + l]
__global__ void prep_w2(const float* __restrict__ dw,
                        const float* __restrict__ wt,
                        float* __restrict__ w2) {
    int i = blockIdx.x * blockDim.x + threadIdx.x;
    if (i < K_NB * 32) {
        int k = i >> 5;
        int c = (i >> 3) & 3;
        int l = i & 7;
        w2[i] = dw[k * 4 + c] * wt[(c * K_NB + k) * OUTC + l];
    }
}

union F2H { float f; __half2 h; };

// points [N,3] fp32 -> ph[N] = {half x, half y, half z, half 0} (8B, aligned)
__global__ void repack_points(const float* __restrict__ pts,
                              v2f* __restrict__ ph, int N) {
    int n = blockIdx.x * blockDim.x + threadIdx.x;
    if (n >= N) return;
    float x = pts[3 * n + 0], y = pts[3 * n + 1], z = pts[3 * n + 2];
    F2H a, b;
    a.h = __floats2half2_rn(x, y);
    b.h = __floats2half2_rn(z, 0.f);
    v2f v; v.x = a.f; v.y = b.f;
    ph[n] = v;
}

__global__ __launch_bounds__(BLK) void conv_main_h(
    const float* __restrict__ points,   // fp32, coalesced self-load
    const v2f*   __restrict__ ph,       // half4-packed points (4 MB: L2-resident)
    const int*   __restrict__ indices,
    const float* __restrict__ w2,
    const float* __restrict__ bias,
    float*       __restrict__ out,
    int N) {
    __shared__ int sidx[BLK * (KT + 1)];  // pitch 17: 2-way bank alias = free

    const int tid = threadIdx.x;
    const int n0  = blockIdx.x * BLK;
    const int n   = n0 + tid;
    const bool valid = n < N;
    const int nc = valid ? n : (N - 1);

    const float px = points[nc * 3 + 0];
    const float py = points[nc * 3 + 1];
    const float pz = points[nc * 3 + 2];

    float acc[OUTC];
#pragma unroll
    for (int l = 0; l < OUTC; ++l) {
        float a = bias[l] + w2[24 + l];           // k=0: dist feature = 1.0
        a = fmaf(px, w2[0 + l], a);
        a = fmaf(py, w2[8 + l], a);
        a = fmaf(pz, w2[16 + l], a);
        acc[l] = a;
    }

    for (int t = 0; t < 5; ++t) {
        __syncthreads();
        // Index staging: nontemporal ON PURPOSE — indices are a 162 MB
        // stream-once; hinting them out of L2 protects the 4 MB ph array.
        // (R4 lesson: nt on the REUSED gather data evicts ph from L2 ->
        //  FETCH 0.53 GB -> 1.65 GB, 299 -> 551 us. Never nt the gather.)
#pragma unroll
        for (int i = 0; i < KT; ++i) {
            int e   = i * BLK + tid;
            int row = e >> 4;
            int col = e & 15;
            int gr  = n0 + row;
            if (gr >= N) gr = N - 1;
            sidx[row * (KT + 1) + col] =
                __builtin_nontemporal_load(&indices[gr * K_NB + 1 + t * KT + col]);
        }
        __syncthreads();

        // phase 1: pull all ids for this thread from LDS
        int ids[KT];
#pragma unroll
        for (int j = 0; j < KT; ++j)
            ids[j] = sidx[tid * (KT + 1) + j];

        // phase 2: issue ALL gathers back-to-back (max outstanding vmem),
        // PLAIN cached loads — ph must stay L2-resident
        v2f r[KT];
#pragma unroll
        for (int j = 0; j < KT; ++j)
            r[j] = ph[ids[j]];

        // phase 3: consume (oldest first, vmcnt waits overlap issue)
#pragma unroll
        for (int j = 0; j < KT; ++j) {
            const int k = 1 + t * KT + j;
            F2H u0, u1; u0.f = r[j].x; u1.f = r[j].y;
            const float2 fxy = __half22float2(u0.h);
            const float  qx = fxy.x, qy = fxy.y;
            const float  qz = __half2float(__low2half(u1.h));
            const float dx = qx - px, dy = qy - py, dz = qz - pz;
            const float dist = fmaf(dx, dx, fmaf(dy, dy, fmaf(dz, dz, 1.0f)));
            const float* __restrict__ w = w2 + k * 32;  // uniform -> s_load
#pragma unroll
            for (int l = 0; l < OUTC; ++l) {
                acc[l] = fmaf(qx, w[l],
                         fmaf(qy, w[8 + l],
                         fmaf(qz, w[16 + l],
                         fmaf(dist, w[24 + l], acc[l]))));
            }
        }
    }

    if (valid) {
        float4* o = (float4*)(out + (long)n * OUTC);
        o[0] = make_float4(acc[0], acc[1], acc[2], acc[3]);
        o[1] = make_float4(acc[4], acc[5], acc[6], acc[7]);
    }
}

// ---------- fp32 fallback if ws too small ----------
__global__ __launch_bounds__(BLK) void conv_main_f32(
    const float* __restrict__ points,
    const int*   __restrict__ indices,
    const float* __restrict__ w2,
    const float* __restrict__ bias,
    float*       __restrict__ out,
    int N) {
    __shared__ int sidx[BLK * (KT + 1)];
    const int tid = threadIdx.x;
    const int n0  = blockIdx.x * BLK;
    const int n   = n0 + tid;
    const bool valid = n < N;
    const int nc = valid ? n : (N - 1);

    const float px = points[nc * 3 + 0];
    const float py = points[nc * 3 + 1];
    const float pz = points[nc * 3 + 2];
    float acc[OUTC];
#pragma unroll
    for (int l = 0; l < OUTC; ++l) {
        float a = bias[l] + w2[24 + l];
        a = fmaf(px, w2[0 + l], a);
        a = fmaf(py, w2[8 + l], a);
        a = fmaf(pz, w2[16 + l], a);
        acc[l] = a;
    }
    for (int t = 0; t < 5; ++t) {
        __syncthreads();
#pragma unroll
        for (int i = 0; i < KT; ++i) {
            int e = i * BLK + tid;
            int row = e >> 4, col = e & 15;
            int gr = n0 + row;
            if (gr >= N) gr = N - 1;
            sidx[row * (KT + 1) + col] = indices[gr * K_NB + 1 + t * KT + col];
        }
        __syncthreads();
#pragma unroll
        for (int j = 0; j < KT; ++j) {
            const int k  = 1 + t * KT + j;
            const int id = sidx[tid * (KT + 1) + j];
            const float qx = points[id * 3 + 0];
            const float qy = points[id * 3 + 1];
            const float qz = points[id * 3 + 2];
            const float dx = qx - px, dy = qy - py, dz = qz - pz;
            const float dist = fmaf(dx, dx, fmaf(dy, dy, fmaf(dz, dz, 1.0f)));
            const float* __restrict__ w = w2 + k * 32;
#pragma unroll
            for (int l = 0; l < OUTC; ++l) {
                acc[l] = fmaf(qx, w[l],
                         fmaf(qy, w[8 + l],
                         fmaf(qz, w[16 + l],
                         fmaf(dist, w[24 + l], acc[l]))));
            }
        }
    }
    if (valid) {
        float4* o = (float4*)(out + (long)n * OUTC);
        o[0] = make_float4(acc[0], acc[1], acc[2], acc[3]);
        o[1] = make_float4(acc[4], acc[5], acc[6], acc[7]);
    }
}

extern "C" void kernel_launch(void* const* d_in, const int* in_sizes, int n_in,
                              void* d_out, int out_size, void* d_ws, size_t ws_size,
                              hipStream_t stream) {
    const float* points  = (const float*)d_in[0];
    const int*   indices = (const int*)  d_in[1];
    const float* dw      = (const float*)d_in[2];
    const float* wt      = (const float*)d_in[3];
    const float* bias    = (const float*)d_in[4];
    float*       out     = (float*)d_out;

    const int N = in_sizes[0] / 3;

    const size_t ph_bytes = (size_t)N * 8;
    const size_t need     = ph_bytes + K_NB * 32 * sizeof(float);

    if (ws_size >= need) {
        v2f*   ph = (v2f*)d_ws;
        float* w2 = (float*)((char*)d_ws + ph_bytes);
        hipLaunchKernelGGL(prep_w2, dim3((K_NB * 32 + BLK - 1) / BLK), dim3(BLK),
                           0, stream, dw, wt, w2);
        hipLaunchKernelGGL(repack_points, dim3((N + BLK - 1) / BLK), dim3(BLK),
                           0, stream, points, ph, N);
        hipLaunchKernelGGL(conv_main_h, dim3((N + BLK - 1) / BLK), dim3(BLK),
                           0, stream, points, ph, indices, w2, bias, out, N);
    } else {
        float* w2 = (float*)d_ws;
        hipLaunchKernelGGL(prep_w2, dim3((K_NB * 32 + BLK - 1) / BLK), dim3(BLK),
                           0, stream, dw, wt, w2);
        hipLaunchKernelGGL(conv_main_f32, dim3((N + BLK - 1) / BLK), dim3(BLK),
                           0, stream, points, indices, w2, bias, out, N);
    }
}